// Round 9
// baseline (1208.984 us; speedup 1.0000x reference)
//
#include <hip/hip_runtime.h>
#include <hip/hip_bf16.h>
#include <stdint.h>

#define BG 64     // graphs
#define NP 256    // nodes per graph
#define DI 256    // in features
#define DO 128    // out features = clusters
#define EP 8192   // edges per graph

// ALL float tensors are FP32 (decoded via R8 probe). Edges int32 (detector covers int64).

__device__ __forceinline__ int ldi(const void* p, size_t i, int i64) {
  return i64 ? (int)((const long long*)p)[i] : ((const int*)p)[i];
}

// ---------------- edge dtype detection (int64 => all odd u32 words zero) ----------------
__global__ void k_edetect(const uint32_t* __restrict__ e, int* __restrict__ flag) {
  __shared__ int cnt;
  if (threadIdx.x == 0) cnt = 0;
  __syncthreads();
  uint32_t w = e[2 * threadIdx.x + 1];
  if (w != 0) atomicAdd(&cnt, 1);
  __syncthreads();
  if (threadIdx.x == 0) *flag = (cnt == 0) ? 1 : 0;   // 1 -> int64
}

// ---------------- A[b][dst][src] += 1 ----------------
__global__ void k_scatter(const void* __restrict__ esrc, const void* __restrict__ edst,
                          const int* __restrict__ flag, float* __restrict__ A) {
  int b = blockIdx.x;
  int i64 = *flag;
  float* Ab = A + (size_t)b * NP * NP;
  for (int e = threadIdx.x; e < EP; e += blockDim.x) {
    int si = ldi(esrc, (size_t)b * EP + e, i64) & (NP - 1);
    int di = ldi(edst, (size_t)b * EP + e, i64) & (NP - 1);
    atomicAdd(Ab + (size_t)di * NP + si, 1.0f);
  }
}

// ---------------- idg = 1/max(rowsum(A),1) ----------------
__global__ void k_invdeg(const float* __restrict__ A, float* __restrict__ idg) {
  int i = blockIdx.x * 256 + threadIdx.x;
  const float* r = A + (size_t)i * NP;
  float s = 0.f;
  for (int j = 0; j < NP; ++j) s += r[j];
  idg[i] = 1.0f / fmaxf(s, 1.0f);
}

// ---------------- agg[bi][f] = idg[bi] * sum_s A[bi][s]*h[b][s][f] ----------------
__global__ __launch_bounds__(256) void k_agg(const float* __restrict__ A,
                                             const float* __restrict__ h,
                                             const float* __restrict__ idg,
                                             float* __restrict__ agg) {
  int bi = blockIdx.x;
  int b = bi >> 8;
  int f = threadIdx.x;
  const float* Ar = A + (size_t)bi * NP;
  const float* hb = h + (size_t)b * NP * DI;
  float acc = 0.f;
  for (int s = 0; s < NP; ++s) {
    float a = Ar[s];
    if (a != 0.f) acc += a * hb[(size_t)s * DI + f];
  }
  agg[(size_t)bi * DI + f] = acc * idg[bi];
}

// ---------------- z = [h|agg]@[Wf|Wp]+b -> L2-normalize, relu (+softmax pool half) -----
__global__ __launch_bounds__(256) void k_z(const float* __restrict__ h,
                                           const float* __restrict__ agg,
                                           const float* __restrict__ Wf,
                                           const float* __restrict__ Wp,
                                           const float* __restrict__ bfe,
                                           const float* __restrict__ bpo,
                                           float* __restrict__ feat,
                                           float* __restrict__ assign) {
  __shared__ float X[2 * DI];
  __shared__ float red[256];
  int bi = blockIdx.x;  // b*NP + n
  int t = threadIdx.x;
  X[t]      = h[(size_t)bi * DI + t];
  X[DI + t] = agg[(size_t)bi * DI + t];
  __syncthreads();

  int half = t >> 7;   // 0 = feat head, 1 = pool head
  int c = t & 127;
  const float* W = half ? Wp : Wf;
  float z = half ? bpo[c] : bfe[c];
  for (int k = 0; k < 2 * DI; ++k) z += X[k] * W[(size_t)k * DO + c];

  red[t] = z * z;
  __syncthreads();
  for (int s = 64; s > 0; s >>= 1) {
    if (c < s) red[t] += red[t + s];
    __syncthreads();
  }
  float inv = 1.0f / fmaxf(sqrtf(red[half << 7]), 1e-12f);
  float v = fmaxf(z * inv, 0.f);
  if (half == 0) feat[(size_t)bi * DO + c] = v;

  __syncthreads();
  red[t] = v;
  __syncthreads();
  for (int s = 64; s > 0; s >>= 1) {
    if (c < s) red[t] = fmaxf(red[t], red[t + s]);
    __syncthreads();
  }
  float mx = red[half << 7];
  float e = __expf(v - mx);
  __syncthreads();
  red[t] = e;
  __syncthreads();
  for (int s = 64; s > 0; s >>= 1) {
    if (c < s) red[t] += red[t + s];
    __syncthreads();
  }
  if (half == 1) assign[(size_t)bi * DO + c] = e / red[128];
}

// ---------------- AS[bi][l] = sum_s A[bi][s]*assign[b][s][l] ----------------
__global__ __launch_bounds__(128) void k_as(const float* __restrict__ A,
                                            const float* __restrict__ assign,
                                            float* __restrict__ AS) {
  int bi = blockIdx.x;
  int b = bi >> 8;
  int l = threadIdx.x;
  const float* Ar = A + (size_t)bi * NP;
  const float* asb = assign + (size_t)b * NP * DO;
  float acc = 0.f;
  for (int s = 0; s < NP; ++s) {
    float a = Ar[s];
    if (a != 0.f) acc += a * asb[(size_t)s * DO + l];
  }
  AS[(size_t)bi * DO + l] = acc;
}

// ---------------- stage[b][k][l] = sum_n assign[b][n][k]*AS[b][n][l] ----------------
__global__ __launch_bounds__(128) void k_blocks(const float* __restrict__ assign,
                                                const float* __restrict__ AS,
                                                float* __restrict__ stage) {
  int bk = blockIdx.x;
  int b = bk >> 7;
  int k = bk & 127;
  int l = threadIdx.x;
  const float* asb = assign + (size_t)b * NP * DO;
  const float* ASb = AS + (size_t)b * NP * DO;
  float acc = 0.f;
  for (int n = 0; n < NP; ++n)
    acc += asb[(size_t)n * DO + k] * ASb[(size_t)n * DO + l];
  stage[((size_t)b * DO + k) * DO + l] = acc;
}

// ---------------- h_pool[b][k][d] (fp32, lives after the adj region) ----------------
__global__ __launch_bounds__(128) void k_hpool(const float* __restrict__ assign,
                                               const float* __restrict__ feat,
                                               float* __restrict__ hp) {
  int bk = blockIdx.x;
  int b = bk >> 7;
  int k = bk & 127;
  int d = threadIdx.x;
  const float* asb = assign + (size_t)b * NP * DO;
  const float* fb = feat + (size_t)b * NP * DO;
  float acc = 0.f;
  for (int n = 0; n < NP; ++n)
    acc += asb[(size_t)n * DO + k] * fb[(size_t)n * DO + d];
  hp[((size_t)b * DO + k) * DO + d] = acc;
}

// ---------------- place staged diag blocks into zeroed fp32 adjacency ----------------
__global__ __launch_bounds__(128) void k_emit(const float* __restrict__ stage,
                                              float* __restrict__ adj) {
  int bk = blockIdx.x;
  int b = bk >> 7;
  int k = bk & 127;
  int l = threadIdx.x;
  adj[(size_t)(b * DO + k) * (BG * DO) + b * DO + l] = stage[((size_t)b * DO + k) * DO + l];
}

extern "C" void kernel_launch(void* const* d_in, const int* in_sizes, int n_in,
                              void* d_out, int out_size, void* d_ws, size_t ws_size,
                              hipStream_t stream) {
  (void)out_size; (void)ws_size;
  // map by element-count signature (equals dict order in practice); biases optional
  int ih = -1, ie[2] = {-1, -1}, iw[2] = {-1, -1}, ib[2] = {-1, -1};
  int ne = 0, nw = 0, nb = 0;
  for (int i = 0; i < n_in; ++i) {
    long long s = in_sizes[i];
    if (s == (long long)BG * NP * DI) { if (ih < 0) ih = i; }
    else if (s == (long long)BG * EP && ne < 2) ie[ne++] = i;
    else if (s == (long long)2 * DI * DO && nw < 2) iw[nw++] = i;
    else if (s == (long long)DO && nb < 2) ib[nb++] = i;
  }
  if (ih < 0 || ne < 2 || nw < 2) {
    ih = 0;
    ie[0] = (n_in > 1) ? 1 : 0;  ie[1] = (n_in > 2) ? 2 : ie[0];
    iw[0] = (n_in > 3) ? 3 : 0;  iw[1] = (n_in > 5) ? 5 : iw[0];
    ib[0] = (n_in > 4) ? 4 : -1; ib[1] = (n_in > 6) ? 6 : -1;
    nb = (ib[1] >= 0) ? 2 : (ib[0] >= 0 ? 1 : 0);
  }
  const float* h    = (const float*)d_in[ih];      // FP32 (R8 probe-decoded)
  const void* esrc  = d_in[ie[0]];
  const void* edst  = d_in[ie[1]];
  const float* Wf   = (const float*)d_in[iw[0]];
  const float* Wp   = (const float*)d_in[iw[1]];
  const float* bfe  = (nb >= 1) ? (const float*)d_in[ib[0]] : nullptr;
  const float* bpo  = (nb >= 2) ? (const float*)d_in[ib[1]] : nullptr;

  float* adj   = (float*)d_out;
  float* hpool = (float*)d_out + (size_t)(BG * DO) * (BG * DO);
  const size_t ADJ_BYTES = (size_t)(BG * DO) * (BG * DO) * sizeof(float);  // 256 MiB

  // Scratch in the dead (zero-until-final-memset) adj region of d_out.
  char* ob = (char*)d_out;
  float* A      = (float*)ob;                          // 16 MiB
  float* agg    = (float*)(ob + ((size_t)16 << 20));   // 16 MiB
  float* feat   = (float*)(ob + ((size_t)32 << 20));   //  8 MiB
  float* assign = (float*)(ob + ((size_t)40 << 20));   //  8 MiB
  float* AS     = (float*)(ob + ((size_t)48 << 20));   //  8 MiB (ends 56 MiB < 256 MiB)

  char* wb = (char*)d_ws;
  float* stage = (float*)wb;                           // 8 MiB
  float* idg   = (float*)(wb + ((size_t)8 << 20));     // 64 KiB
  int* eflag   = (int*)(wb + ((size_t)8 << 20) + 65536);
  float* zbias = (float*)(wb + ((size_t)8 << 20) + 65536 + 256);  // 128 zeros fallback

  hipMemsetAsync(zbias, 0, DO * sizeof(float), stream);
  if (!bfe) bfe = zbias;
  if (!bpo) bpo = zbias;

  k_edetect<<<1, 256, 0, stream>>>((const uint32_t*)esrc, eflag);
  hipMemsetAsync(A, 0, (size_t)BG * NP * NP * sizeof(float), stream);
  k_scatter<<<BG, 256, 0, stream>>>(esrc, edst, eflag, A);
  k_invdeg<<<BG * NP / 256, 256, 0, stream>>>(A, idg);
  k_agg<<<BG * NP, 256, 0, stream>>>(A, h, idg, agg);
  k_z<<<BG * NP, 256, 0, stream>>>(h, agg, Wf, Wp, bfe, bpo, feat, assign);
  k_as<<<BG * NP, 128, 0, stream>>>(A, assign, AS);
  k_blocks<<<BG * DO, 128, 0, stream>>>(assign, AS, stage);
  k_hpool<<<BG * DO, 128, 0, stream>>>(assign, feat, hpool);

  hipMemsetAsync(adj, 0, ADJ_BYTES, stream);                  // scratch is dead now
  k_emit<<<BG * DO, 128, 0, stream>>>(stage, adj);
}

// Round 10
// 865.455 us; speedup vs baseline: 1.3969x; 1.3969x over previous
//
#include <hip/hip_runtime.h>
#include <hip/hip_bf16.h>
#include <stdint.h>

#define BG 64     // graphs
#define NP 256    // nodes per graph
#define DI 256    // in features
#define DO 128    // out features = clusters
#define EP 8192   // edges per graph

// ALL float tensors are FP32 (R8 probe-decoded; R9 passed). Edges int32 (+int64 detector).

__device__ __forceinline__ int ldi(const void* p, size_t i, int i64) {
  return i64 ? (int)((const long long*)p)[i] : ((const int*)p)[i];
}

// ---------------- edge dtype detection (int64 => all odd u32 words zero) ----------------
__global__ void k_edetect(const uint32_t* __restrict__ e, int* __restrict__ flag) {
  __shared__ int cnt;
  if (threadIdx.x == 0) cnt = 0;
  __syncthreads();
  uint32_t w = e[2 * threadIdx.x + 1];
  if (w != 0) atomicAdd(&cnt, 1);
  __syncthreads();
  if (threadIdx.x == 0) *flag = (cnt == 0) ? 1 : 0;   // 1 -> int64
}

// ---------------- A[b][dst][src] += 1 ----------------
__global__ void k_scatter(const void* __restrict__ esrc, const void* __restrict__ edst,
                          const int* __restrict__ flag, float* __restrict__ A) {
  int b = blockIdx.x;
  int i64 = *flag;
  float* Ab = A + (size_t)b * NP * NP;
  for (int e = threadIdx.x; e < EP; e += blockDim.x) {
    int si = ldi(esrc, (size_t)b * EP + e, i64) & (NP - 1);
    int di = ldi(edst, (size_t)b * EP + e, i64) & (NP - 1);
    atomicAdd(Ab + (size_t)di * NP + si, 1.0f);
  }
}

// ---------------- idg = 1/max(rowsum(A),1) ----------------
__global__ void k_invdeg(const float* __restrict__ A, float* __restrict__ idg) {
  int i = blockIdx.x * 256 + threadIdx.x;
  const float* r = A + (size_t)i * NP;
  float s = 0.f;
  for (int j = 0; j < NP; ++j) s += r[j];
  idg[i] = 1.0f / fmaxf(s, 1.0f);
}

// ---------------- agg[bi][f] = idg[bi] * sum_s A[bi][s]*h[b][s][f] (sparse-guarded) ----
__global__ __launch_bounds__(256) void k_agg(const float* __restrict__ A,
                                             const float* __restrict__ h,
                                             const float* __restrict__ idg,
                                             float* __restrict__ agg) {
  int bi = blockIdx.x;
  int b = bi >> 8;
  int f = threadIdx.x;
  const float* Ar = A + (size_t)bi * NP;
  const float* hb = h + (size_t)b * NP * DI;
  float acc = 0.f;
  for (int s = 0; s < NP; ++s) {
    float a = Ar[s];                 // block-uniform -> whole wave skips zeros
    if (a != 0.f) acc += a * hb[(size_t)s * DI + f];
  }
  agg[(size_t)bi * DI + f] = acc * idg[bi];
}

// ---------------- Z = [h|agg] @ [Wf|Wp] ; tiled GEMM 32x256, thread 4x8 ----------------
// Kills the L2-BW bound of old k_z: W staged in LDS once per 32 rows (traffic /32).
__global__ __launch_bounds__(256) void k_gemm_z(const float* __restrict__ h,
                                                const float* __restrict__ agg,
                                                const float* __restrict__ Wf,
                                                const float* __restrict__ Wp,
                                                float* __restrict__ Z) {
  __shared__ __align__(16) float Xs[32][36];    // [k][row]
  __shared__ __align__(16) float Ws[32][264];   // [k][col]
  int r0 = blockIdx.x * 32;
  int t = threadIdx.x;
  int rg = t >> 5;     // 0..7  -> rows rg*4..rg*4+3
  int cg = t & 31;     // 0..31 -> cols cg*8..cg*8+7
  float acc[4][8] = {};
  for (int kc = 0; kc < 2 * DI; kc += 32) {
    __syncthreads();
    {  // X chunk: 32 rows x 32 k, 4 elems/thread (one float4)
      int r = t >> 3;
      int kk = (t & 7) * 4;
      const float* src = (kc < DI) ? &h[(size_t)(r0 + r) * DI + kc + kk]
                                   : &agg[(size_t)(r0 + r) * DI + (kc - DI) + kk];
      float4 v = *(const float4*)src;
      Xs[kk + 0][r] = v.x; Xs[kk + 1][r] = v.y; Xs[kk + 2][r] = v.z; Xs[kk + 3][r] = v.w;
    }
    {  // W chunk: 32 k x 256 c, 32 elems/thread (8 float4)
      int k = t >> 3;
      int cbase = (t & 7) * 32;
      const float* srcW = (cbase < DO) ? &Wf[(size_t)(kc + k) * DO + cbase]
                                       : &Wp[(size_t)(kc + k) * DO + cbase - DO];
#pragma unroll
      for (int j = 0; j < 8; ++j)
        *(float4*)&Ws[k][cbase + j * 4] = *(const float4*)(srcW + j * 4);
    }
    __syncthreads();
#pragma unroll
    for (int kk = 0; kk < 32; ++kk) {
      float a[4], w[8];
      *(float4*)&a[0] = *(const float4*)&Xs[kk][rg * 4];
      *(float4*)&w[0] = *(const float4*)&Ws[kk][cg * 8];
      *(float4*)&w[4] = *(const float4*)&Ws[kk][cg * 8 + 4];
#pragma unroll
      for (int i = 0; i < 4; ++i)
#pragma unroll
        for (int j = 0; j < 8; ++j)
          acc[i][j] += a[i] * w[j];
    }
  }
#pragma unroll
  for (int i = 0; i < 4; ++i) {
    float* dst = &Z[(size_t)(r0 + rg * 4 + i) * 256 + cg * 8];
    *(float4*)dst = *(float4*)&acc[i][0];
    *(float4*)(dst + 4) = *(float4*)&acc[i][4];
  }
}

// ---------------- epilogue: +bias, L2-normalize per half, relu; pool half softmax -----
__global__ __launch_bounds__(256) void k_epi(const float* __restrict__ Z,
                                             const float* __restrict__ bfe,
                                             const float* __restrict__ bpo,
                                             float* __restrict__ feat,
                                             float* __restrict__ assign) {
  __shared__ float red[256];
  int bi = blockIdx.x;  // b*NP + n
  int t = threadIdx.x;
  int half = t >> 7;    // 0 = feat head, 1 = pool head
  int c = t & 127;
  float z = Z[(size_t)bi * 256 + t] + (half ? bpo[c] : bfe[c]);

  red[t] = z * z;
  __syncthreads();
  for (int s = 64; s > 0; s >>= 1) {
    if (c < s) red[t] += red[t + s];
    __syncthreads();
  }
  float inv = 1.0f / fmaxf(sqrtf(red[half << 7]), 1e-12f);
  float v = fmaxf(z * inv, 0.f);
  if (half == 0) feat[(size_t)bi * DO + c] = v;

  __syncthreads();
  red[t] = v;
  __syncthreads();
  for (int s = 64; s > 0; s >>= 1) {
    if (c < s) red[t] = fmaxf(red[t], red[t + s]);
    __syncthreads();
  }
  float mx = red[half << 7];
  float e = __expf(v - mx);
  __syncthreads();
  red[t] = e;
  __syncthreads();
  for (int s = 64; s > 0; s >>= 1) {
    if (c < s) red[t] += red[t + s];
    __syncthreads();
  }
  if (half == 1) assign[(size_t)bi * DO + c] = e / red[128];
}

// ---------------- AS[bi][l] = sum_s A[bi][s]*assign[b][s][l] (sparse-guarded) ----------
__global__ __launch_bounds__(128) void k_as(const float* __restrict__ A,
                                            const float* __restrict__ assign,
                                            float* __restrict__ AS) {
  int bi = blockIdx.x;
  int b = bi >> 8;
  int l = threadIdx.x;
  const float* Ar = A + (size_t)bi * NP;
  const float* asb = assign + (size_t)b * NP * DO;
  float acc = 0.f;
  for (int s = 0; s < NP; ++s) {
    float a = Ar[s];
    if (a != 0.f) acc += a * asb[(size_t)s * DO + l];
  }
  AS[(size_t)bi * DO + l] = acc;
}

// ---------------- pooling GEMMs: out = assign^T @ Y ; tiled 64x128/block ----------------
// blockIdx.x = mt (0/1) + 2*which; which 0 -> stage (adj blocks, Y=AS), 1 -> hpool (Y=feat)
__global__ __launch_bounds__(256) void k_pool(const float* __restrict__ assign,
                                              const float* __restrict__ AS,
                                              const float* __restrict__ feat,
                                              float* __restrict__ stage,
                                              float* __restrict__ hpool) {
  __shared__ __align__(16) float Ps[32][68];    // [n][m]
  __shared__ __align__(16) float Ys[32][132];   // [n][d]
  int b = blockIdx.y;
  int mt = blockIdx.x & 1;
  int which = blockIdx.x >> 1;
  const float* Y = which ? feat : AS;
  int m0 = mt * 64;
  int t = threadIdx.x;
  int tr = t >> 4, tc = t & 15;   // 4 rows x 8 cols per thread
  float acc[4][8] = {};
  for (int nc = 0; nc < NP; nc += 32) {
    __syncthreads();
    {  // P chunk: 32 n x 64 m, 8/thread (2 float4): P[n][m] = assign[(b*NP+nc+n)*DO + m0+m]
      int n = t >> 3;
      int mseg = (t & 7) * 8;
      const float* src = &assign[((size_t)b * NP + nc + n) * DO + m0 + mseg];
      *(float4*)&Ps[n][mseg] = *(const float4*)src;
      *(float4*)&Ps[n][mseg + 4] = *(const float4*)(src + 4);
    }
    for (int idx = t; idx < 32 * 128; idx += 256) {  // Y chunk: 32 n x 128 d
      int d = idx & 127, n = idx >> 7;
      Ys[n][d] = Y[((size_t)b * NP + nc + n) * DO + d];
    }
    __syncthreads();
#pragma unroll
    for (int n = 0; n < 32; ++n) {
      float a[4], w[8];
      *(float4*)&a[0] = *(const float4*)&Ps[n][tr * 4];
      *(float4*)&w[0] = *(const float4*)&Ys[n][tc * 8];
      *(float4*)&w[4] = *(const float4*)&Ys[n][tc * 8 + 4];
#pragma unroll
      for (int i = 0; i < 4; ++i)
#pragma unroll
        for (int j = 0; j < 8; ++j)
          acc[i][j] += a[i] * w[j];
    }
  }
  float* out = which ? &hpool[((size_t)b * DO + m0 + tr * 4) * DO + tc * 8]
                     : &stage[((size_t)b * DO + m0 + tr * 4) * DO + tc * 8];
#pragma unroll
  for (int i = 0; i < 4; ++i) {
    *(float4*)(out + (size_t)i * DO) = *(float4*)&acc[i][0];
    *(float4*)(out + (size_t)i * DO + 4) = *(float4*)&acc[i][4];
  }
}

// ---------------- place staged diag blocks into zeroed fp32 adjacency ----------------
__global__ __launch_bounds__(128) void k_emit(const float* __restrict__ stage,
                                              float* __restrict__ adj) {
  int bk = blockIdx.x;
  int b = bk >> 7;
  int k = bk & 127;
  int l = threadIdx.x;
  adj[(size_t)(b * DO + k) * (BG * DO) + b * DO + l] = stage[((size_t)b * DO + k) * DO + l];
}

extern "C" void kernel_launch(void* const* d_in, const int* in_sizes, int n_in,
                              void* d_out, int out_size, void* d_ws, size_t ws_size,
                              hipStream_t stream) {
  (void)out_size; (void)ws_size;
  // map by element-count signature (== dict order in practice); biases optional
  int ih = -1, ie[2] = {-1, -1}, iw[2] = {-1, -1}, ib[2] = {-1, -1};
  int ne = 0, nw = 0, nb = 0;
  for (int i = 0; i < n_in; ++i) {
    long long s = in_sizes[i];
    if (s == (long long)BG * NP * DI) { if (ih < 0) ih = i; }
    else if (s == (long long)BG * EP && ne < 2) ie[ne++] = i;
    else if (s == (long long)2 * DI * DO && nw < 2) iw[nw++] = i;
    else if (s == (long long)DO && nb < 2) ib[nb++] = i;
  }
  if (ih < 0 || ne < 2 || nw < 2) {
    ih = 0;
    ie[0] = (n_in > 1) ? 1 : 0;  ie[1] = (n_in > 2) ? 2 : ie[0];
    iw[0] = (n_in > 3) ? 3 : 0;  iw[1] = (n_in > 5) ? 5 : iw[0];
    ib[0] = (n_in > 4) ? 4 : -1; ib[1] = (n_in > 6) ? 6 : -1;
    nb = (ib[1] >= 0) ? 2 : (ib[0] >= 0 ? 1 : 0);
  }
  const float* h    = (const float*)d_in[ih];
  const void* esrc  = d_in[ie[0]];
  const void* edst  = d_in[ie[1]];
  const float* Wf   = (const float*)d_in[iw[0]];
  const float* Wp   = (const float*)d_in[iw[1]];
  const float* bfe  = (nb >= 1) ? (const float*)d_in[ib[0]] : nullptr;
  const float* bpo  = (nb >= 2) ? (const float*)d_in[ib[1]] : nullptr;

  float* adj   = (float*)d_out;
  float* hpool = (float*)d_out + (size_t)(BG * DO) * (BG * DO);
  const size_t ADJ_BYTES = (size_t)(BG * DO) * (BG * DO) * sizeof(float);  // 256 MiB

  // Scratch in the dead (zero-until-final-memset) adj region of d_out.
  char* ob = (char*)d_out;
  float* A      = (float*)ob;                          // 16 MiB
  float* agg    = (float*)(ob + ((size_t)16 << 20));   // 16 MiB
  float* feat   = (float*)(ob + ((size_t)32 << 20));   //  8 MiB
  float* assign = (float*)(ob + ((size_t)40 << 20));   //  8 MiB
  float* AS     = (float*)(ob + ((size_t)48 << 20));   //  8 MiB
  float* Z      = (float*)(ob + ((size_t)56 << 20));   // 16 MiB (ends 72 MiB < 256 MiB)

  char* wb = (char*)d_ws;
  float* stage = (float*)wb;                           // 8 MiB
  float* idg   = (float*)(wb + ((size_t)8 << 20));     // 64 KiB
  int* eflag   = (int*)(wb + ((size_t)8 << 20) + 65536);
  float* zbias = (float*)(wb + ((size_t)8 << 20) + 65536 + 256);

  hipMemsetAsync(zbias, 0, DO * sizeof(float), stream);
  if (!bfe) bfe = zbias;
  if (!bpo) bpo = zbias;

  k_edetect<<<1, 256, 0, stream>>>((const uint32_t*)esrc, eflag);
  hipMemsetAsync(A, 0, (size_t)BG * NP * NP * sizeof(float), stream);
  k_scatter<<<BG, 256, 0, stream>>>(esrc, edst, eflag, A);
  k_invdeg<<<BG * NP / 256, 256, 0, stream>>>(A, idg);
  k_agg<<<BG * NP, 256, 0, stream>>>(A, h, idg, agg);
  k_gemm_z<<<BG * NP / 32, 256, 0, stream>>>(h, agg, Wf, Wp, Z);
  k_epi<<<BG * NP, 256, 0, stream>>>(Z, bfe, bpo, feat, assign);
  k_as<<<BG * NP, 128, 0, stream>>>(A, assign, AS);
  k_pool<<<dim3(4, BG), 256, 0, stream>>>(assign, AS, feat, stage, hpool);

  hipMemsetAsync(adj, 0, ADJ_BYTES, stream);                  // scratch is dead now
  k_emit<<<BG * DO, 128, 0, stream>>>(stage, adj);
}

// Round 11
// 538.325 us; speedup vs baseline: 2.2458x; 1.6077x over previous
//
#include <hip/hip_runtime.h>
#include <hip/hip_bf16.h>
#include <stdint.h>

#define BG 64     // graphs
#define NP 256    // nodes per graph
#define DI 256    // in features
#define DO 128    // out features = clusters
#define EP 8192   // edges per graph

// ALL float tensors are FP32 (R8 probe-decoded; R9/R10 passed). Edges int32 (+int64 detector).

__device__ __forceinline__ int ldi(const void* p, size_t i, int i64) {
  return i64 ? (int)((const long long*)p)[i] : ((const int*)p)[i];
}

// ---------------- edge dtype detection (int64 => all odd u32 words zero) ----------------
__global__ void k_edetect(const uint32_t* __restrict__ e, int* __restrict__ flag) {
  __shared__ int cnt;
  if (threadIdx.x == 0) cnt = 0;
  __syncthreads();
  uint32_t w = e[2 * threadIdx.x + 1];
  if (w != 0) atomicAdd(&cnt, 1);
  __syncthreads();
  if (threadIdx.x == 0) *flag = (cnt == 0) ? 1 : 0;   // 1 -> int64
}

// ---------------- A[b][dst][src] += 1 ----------------
__global__ void k_scatter(const void* __restrict__ esrc, const void* __restrict__ edst,
                          const int* __restrict__ flag, float* __restrict__ A) {
  int b = blockIdx.x;
  int i64 = *flag;
  float* Ab = A + (size_t)b * NP * NP;
  for (int e = threadIdx.x; e < EP; e += blockDim.x) {
    int si = ldi(esrc, (size_t)b * EP + e, i64) & (NP - 1);
    int di = ldi(edst, (size_t)b * EP + e, i64) & (NP - 1);
    atomicAdd(Ab + (size_t)di * NP + si, 1.0f);
  }
}

// ---------------- idg = 1/max(rowsum(A),1) ----------------
__global__ void k_invdeg(const float* __restrict__ A, float* __restrict__ idg) {
  int i = blockIdx.x * 256 + threadIdx.x;
  const float* r = A + (size_t)i * NP;
  float s = 0.f;
  for (int j = 0; j < NP; ++j) s += r[j];
  idg[i] = 1.0f / fmaxf(s, 1.0f);
}

// ---------------- agg = rowscale(A @ h) ; dense tiled GEMM 64x128, thread 4x8 ----------
// grid: (8, BG) -> rt = bx&3 (row tile), ct = bx>>2 (col tile of DI)
__global__ __launch_bounds__(256) void k_gemm_agg(const float* __restrict__ A,
                                                  const float* __restrict__ h,
                                                  const float* __restrict__ idg,
                                                  float* __restrict__ agg) {
  __shared__ __align__(16) float As[32][68];    // [k][r]
  __shared__ __align__(16) float Hs[32][132];   // [k][f]
  int b = blockIdx.y;
  int r0 = (blockIdx.x & 3) * 64;
  int f0 = (blockIdx.x >> 2) * 128;
  int t = threadIdx.x;
  int tr = t >> 4, tc = t & 15;   // 4 rows x 8 cols per thread
  float acc[4][8] = {};
  const float* Ab = A + (size_t)b * NP * NP;
  const float* hb = h + (size_t)b * NP * DI;
  for (int kc = 0; kc < NP; kc += 32) {
    __syncthreads();
    {  // A tile: 64 r x 32 k, 8/thread (2 float4), stored transposed [k][r]
      int r = t >> 2;
      int ks = (t & 3) * 8;
      const float* src = &Ab[(size_t)(r0 + r) * NP + kc + ks];
      float4 v0 = *(const float4*)src;
      float4 v1 = *(const float4*)(src + 4);
      As[ks + 0][r] = v0.x; As[ks + 1][r] = v0.y; As[ks + 2][r] = v0.z; As[ks + 3][r] = v0.w;
      As[ks + 4][r] = v1.x; As[ks + 5][r] = v1.y; As[ks + 6][r] = v1.z; As[ks + 7][r] = v1.w;
    }
    {  // H tile: 32 k x 128 f, 16/thread (4 float4)
      int k = t >> 3;
      int fs = (t & 7) * 16;
      const float* src = &hb[(size_t)(kc + k) * DI + f0 + fs];
#pragma unroll
      for (int j = 0; j < 4; ++j)
        *(float4*)&Hs[k][fs + j * 4] = *(const float4*)(src + j * 4);
    }
    __syncthreads();
#pragma unroll
    for (int k = 0; k < 32; ++k) {
      float a[4], w[8];
      *(float4*)&a[0] = *(const float4*)&As[k][tr * 4];
      *(float4*)&w[0] = *(const float4*)&Hs[k][tc * 8];
      *(float4*)&w[4] = *(const float4*)&Hs[k][tc * 8 + 4];
#pragma unroll
      for (int i = 0; i < 4; ++i)
#pragma unroll
        for (int j = 0; j < 8; ++j)
          acc[i][j] += a[i] * w[j];
    }
  }
#pragma unroll
  for (int i = 0; i < 4; ++i) {
    int gi = r0 + tr * 4 + i;
    float sc = idg[b * NP + gi];
    float* dst = &agg[((size_t)b * NP + gi) * DI + f0 + tc * 8];
    float o0[4] = { acc[i][0] * sc, acc[i][1] * sc, acc[i][2] * sc, acc[i][3] * sc };
    float o1[4] = { acc[i][4] * sc, acc[i][5] * sc, acc[i][6] * sc, acc[i][7] * sc };
    *(float4*)dst = *(float4*)o0;
    *(float4*)(dst + 4) = *(float4*)o1;
  }
}

// ---------------- AS = A @ assign ; dense tiled GEMM 64x128, thread 4x8 ----------------
// grid: (4, BG) -> row tiles only (DO = 128 = one col tile)
__global__ __launch_bounds__(256) void k_gemm_as(const float* __restrict__ A,
                                                 const float* __restrict__ assign,
                                                 float* __restrict__ AS) {
  __shared__ __align__(16) float As[32][68];    // [k][r]
  __shared__ __align__(16) float Bs[32][132];   // [k][l]
  int b = blockIdx.y;
  int r0 = blockIdx.x * 64;
  int t = threadIdx.x;
  int tr = t >> 4, tc = t & 15;
  float acc[4][8] = {};
  const float* Ab = A + (size_t)b * NP * NP;
  const float* asb = assign + (size_t)b * NP * DO;
  for (int kc = 0; kc < NP; kc += 32) {
    __syncthreads();
    {  // A tile: 64 r x 32 k, transposed
      int r = t >> 2;
      int ks = (t & 3) * 8;
      const float* src = &Ab[(size_t)(r0 + r) * NP + kc + ks];
      float4 v0 = *(const float4*)src;
      float4 v1 = *(const float4*)(src + 4);
      As[ks + 0][r] = v0.x; As[ks + 1][r] = v0.y; As[ks + 2][r] = v0.z; As[ks + 3][r] = v0.w;
      As[ks + 4][r] = v1.x; As[ks + 5][r] = v1.y; As[ks + 6][r] = v1.z; As[ks + 7][r] = v1.w;
    }
    {  // assign tile: 32 k x 128 l, 16/thread (4 float4)
      int k = t >> 3;
      int ls = (t & 7) * 16;
      const float* src = &asb[(size_t)(kc + k) * DO + ls];
#pragma unroll
      for (int j = 0; j < 4; ++j)
        *(float4*)&Bs[k][ls + j * 4] = *(const float4*)(src + j * 4);
    }
    __syncthreads();
#pragma unroll
    for (int k = 0; k < 32; ++k) {
      float a[4], w[8];
      *(float4*)&a[0] = *(const float4*)&As[k][tr * 4];
      *(float4*)&w[0] = *(const float4*)&Bs[k][tc * 8];
      *(float4*)&w[4] = *(const float4*)&Bs[k][tc * 8 + 4];
#pragma unroll
      for (int i = 0; i < 4; ++i)
#pragma unroll
        for (int j = 0; j < 8; ++j)
          acc[i][j] += a[i] * w[j];
    }
  }
#pragma unroll
  for (int i = 0; i < 4; ++i) {
    float* dst = &AS[((size_t)b * NP + r0 + tr * 4 + i) * DO + tc * 8];
    *(float4*)dst = *(float4*)&acc[i][0];
    *(float4*)(dst + 4) = *(float4*)&acc[i][4];
  }
}

// ---------------- Z = [h|agg] @ [Wf|Wp] ; tiled GEMM 32x256, thread 4x8 ----------------
__global__ __launch_bounds__(256) void k_gemm_z(const float* __restrict__ h,
                                                const float* __restrict__ agg,
                                                const float* __restrict__ Wf,
                                                const float* __restrict__ Wp,
                                                float* __restrict__ Z) {
  __shared__ __align__(16) float Xs[32][36];    // [k][row]
  __shared__ __align__(16) float Ws[32][264];   // [k][col]
  int r0 = blockIdx.x * 32;
  int t = threadIdx.x;
  int rg = t >> 5;     // 0..7  -> rows rg*4..rg*4+3
  int cg = t & 31;     // 0..31 -> cols cg*8..cg*8+7
  float acc[4][8] = {};
  for (int kc = 0; kc < 2 * DI; kc += 32) {
    __syncthreads();
    {  // X chunk: 32 rows x 32 k
      int r = t >> 3;
      int kk = (t & 7) * 4;
      const float* src = (kc < DI) ? &h[(size_t)(r0 + r) * DI + kc + kk]
                                   : &agg[(size_t)(r0 + r) * DI + (kc - DI) + kk];
      float4 v = *(const float4*)src;
      Xs[kk + 0][r] = v.x; Xs[kk + 1][r] = v.y; Xs[kk + 2][r] = v.z; Xs[kk + 3][r] = v.w;
    }
    {  // W chunk: 32 k x 256 c
      int k = t >> 3;
      int cbase = (t & 7) * 32;
      const float* srcW = (cbase < DO) ? &Wf[(size_t)(kc + k) * DO + cbase]
                                       : &Wp[(size_t)(kc + k) * DO + cbase - DO];
#pragma unroll
      for (int j = 0; j < 8; ++j)
        *(float4*)&Ws[k][cbase + j * 4] = *(const float4*)(srcW + j * 4);
    }
    __syncthreads();
#pragma unroll
    for (int kk = 0; kk < 32; ++kk) {
      float a[4], w[8];
      *(float4*)&a[0] = *(const float4*)&Xs[kk][rg * 4];
      *(float4*)&w[0] = *(const float4*)&Ws[kk][cg * 8];
      *(float4*)&w[4] = *(const float4*)&Ws[kk][cg * 8 + 4];
#pragma unroll
      for (int i = 0; i < 4; ++i)
#pragma unroll
        for (int j = 0; j < 8; ++j)
          acc[i][j] += a[i] * w[j];
    }
  }
#pragma unroll
  for (int i = 0; i < 4; ++i) {
    float* dst = &Z[(size_t)(r0 + rg * 4 + i) * 256 + cg * 8];
    *(float4*)dst = *(float4*)&acc[i][0];
    *(float4*)(dst + 4) = *(float4*)&acc[i][4];
  }
}

// ---------------- epilogue: +bias, L2-normalize per half, relu; pool half softmax -----
__global__ __launch_bounds__(256) void k_epi(const float* __restrict__ Z,
                                             const float* __restrict__ bfe,
                                             const float* __restrict__ bpo,
                                             float* __restrict__ feat,
                                             float* __restrict__ assign) {
  __shared__ float red[256];
  int bi = blockIdx.x;  // b*NP + n
  int t = threadIdx.x;
  int half = t >> 7;    // 0 = feat head, 1 = pool head
  int c = t & 127;
  float z = Z[(size_t)bi * 256 + t] + (half ? bpo[c] : bfe[c]);

  red[t] = z * z;
  __syncthreads();
  for (int s = 64; s > 0; s >>= 1) {
    if (c < s) red[t] += red[t + s];
    __syncthreads();
  }
  float inv = 1.0f / fmaxf(sqrtf(red[half << 7]), 1e-12f);
  float v = fmaxf(z * inv, 0.f);
  if (half == 0) feat[(size_t)bi * DO + c] = v;

  __syncthreads();
  red[t] = v;
  __syncthreads();
  for (int s = 64; s > 0; s >>= 1) {
    if (c < s) red[t] = fmaxf(red[t], red[t + s]);
    __syncthreads();
  }
  float mx = red[half << 7];
  float e = __expf(v - mx);
  __syncthreads();
  red[t] = e;
  __syncthreads();
  for (int s = 64; s > 0; s >>= 1) {
    if (c < s) red[t] += red[t + s];
    __syncthreads();
  }
  if (half == 1) assign[(size_t)bi * DO + c] = e / red[128];
}

// ---------------- pooling GEMMs: out = assign^T @ Y ; tiled 64x128/block ----------------
__global__ __launch_bounds__(256) void k_pool(const float* __restrict__ assign,
                                              const float* __restrict__ AS,
                                              const float* __restrict__ feat,
                                              float* __restrict__ stage,
                                              float* __restrict__ hpool) {
  __shared__ __align__(16) float Ps[32][68];    // [n][m]
  __shared__ __align__(16) float Ys[32][132];   // [n][d]
  int b = blockIdx.y;
  int mt = blockIdx.x & 1;
  int which = blockIdx.x >> 1;
  const float* Y = which ? feat : AS;
  int m0 = mt * 64;
  int t = threadIdx.x;
  int tr = t >> 4, tc = t & 15;
  float acc[4][8] = {};
  for (int nc = 0; nc < NP; nc += 32) {
    __syncthreads();
    {  // P chunk: 32 n x 64 m
      int n = t >> 3;
      int mseg = (t & 7) * 8;
      const float* src = &assign[((size_t)b * NP + nc + n) * DO + m0 + mseg];
      *(float4*)&Ps[n][mseg] = *(const float4*)src;
      *(float4*)&Ps[n][mseg + 4] = *(const float4*)(src + 4);
    }
    {  // Y chunk: 32 n x 128 d, 16/thread
      int n = t >> 3;
      int ds = (t & 7) * 16;
      const float* src = &Y[((size_t)b * NP + nc + n) * DO + ds];
#pragma unroll
      for (int j = 0; j < 4; ++j)
        *(float4*)&Ys[n][ds + j * 4] = *(const float4*)(src + j * 4);
    }
    __syncthreads();
#pragma unroll
    for (int n = 0; n < 32; ++n) {
      float a[4], w[8];
      *(float4*)&a[0] = *(const float4*)&Ps[n][tr * 4];
      *(float4*)&w[0] = *(const float4*)&Ys[n][tc * 8];
      *(float4*)&w[4] = *(const float4*)&Ys[n][tc * 8 + 4];
#pragma unroll
      for (int i = 0; i < 4; ++i)
#pragma unroll
        for (int j = 0; j < 8; ++j)
          acc[i][j] += a[i] * w[j];
    }
  }
  float* out = which ? &hpool[((size_t)b * DO + m0 + tr * 4) * DO + tc * 8]
                     : &stage[((size_t)b * DO + m0 + tr * 4) * DO + tc * 8];
#pragma unroll
  for (int i = 0; i < 4; ++i) {
    *(float4*)(out + (size_t)i * DO) = *(float4*)&acc[i][0];
    *(float4*)(out + (size_t)i * DO + 4) = *(float4*)&acc[i][4];
  }
}

// ---------------- place staged diag blocks into zeroed fp32 adjacency ----------------
__global__ __launch_bounds__(128) void k_emit(const float* __restrict__ stage,
                                              float* __restrict__ adj) {
  int bk = blockIdx.x;
  int b = bk >> 7;
  int k = bk & 127;
  int l = threadIdx.x;
  adj[(size_t)(b * DO + k) * (BG * DO) + b * DO + l] = stage[((size_t)b * DO + k) * DO + l];
}

extern "C" void kernel_launch(void* const* d_in, const int* in_sizes, int n_in,
                              void* d_out, int out_size, void* d_ws, size_t ws_size,
                              hipStream_t stream) {
  (void)out_size; (void)ws_size;
  int ih = -1, ie[2] = {-1, -1}, iw[2] = {-1, -1}, ib[2] = {-1, -1};
  int ne = 0, nw = 0, nb = 0;
  for (int i = 0; i < n_in; ++i) {
    long long s = in_sizes[i];
    if (s == (long long)BG * NP * DI) { if (ih < 0) ih = i; }
    else if (s == (long long)BG * EP && ne < 2) ie[ne++] = i;
    else if (s == (long long)2 * DI * DO && nw < 2) iw[nw++] = i;
    else if (s == (long long)DO && nb < 2) ib[nb++] = i;
  }
  if (ih < 0 || ne < 2 || nw < 2) {
    ih = 0;
    ie[0] = (n_in > 1) ? 1 : 0;  ie[1] = (n_in > 2) ? 2 : ie[0];
    iw[0] = (n_in > 3) ? 3 : 0;  iw[1] = (n_in > 5) ? 5 : iw[0];
    ib[0] = (n_in > 4) ? 4 : -1; ib[1] = (n_in > 6) ? 6 : -1;
    nb = (ib[1] >= 0) ? 2 : (ib[0] >= 0 ? 1 : 0);
  }
  const float* h    = (const float*)d_in[ih];
  const void* esrc  = d_in[ie[0]];
  const void* edst  = d_in[ie[1]];
  const float* Wf   = (const float*)d_in[iw[0]];
  const float* Wp   = (const float*)d_in[iw[1]];
  const float* bfe  = (nb >= 1) ? (const float*)d_in[ib[0]] : nullptr;
  const float* bpo  = (nb >= 2) ? (const float*)d_in[ib[1]] : nullptr;

  float* adj   = (float*)d_out;
  float* hpool = (float*)d_out + (size_t)(BG * DO) * (BG * DO);
  const size_t ADJ_BYTES = (size_t)(BG * DO) * (BG * DO) * sizeof(float);  // 256 MiB

  // Scratch in the dead (zero-until-final-memset) adj region of d_out.
  char* ob = (char*)d_out;
  float* A      = (float*)ob;                          // 16 MiB
  float* agg    = (float*)(ob + ((size_t)16 << 20));   // 16 MiB
  float* feat   = (float*)(ob + ((size_t)32 << 20));   //  8 MiB
  float* assign = (float*)(ob + ((size_t)40 << 20));   //  8 MiB
  float* AS     = (float*)(ob + ((size_t)48 << 20));   //  8 MiB
  float* Z      = (float*)(ob + ((size_t)56 << 20));   // 16 MiB (ends 72 MiB < 256 MiB)

  char* wb = (char*)d_ws;
  float* stage = (float*)wb;                           // 8 MiB
  float* idg   = (float*)(wb + ((size_t)8 << 20));     // 64 KiB
  int* eflag   = (int*)(wb + ((size_t)8 << 20) + 65536);
  float* zbias = (float*)(wb + ((size_t)8 << 20) + 65536 + 256);

  hipMemsetAsync(zbias, 0, DO * sizeof(float), stream);
  if (!bfe) bfe = zbias;
  if (!bpo) bpo = zbias;

  k_edetect<<<1, 256, 0, stream>>>((const uint32_t*)esrc, eflag);
  hipMemsetAsync(A, 0, (size_t)BG * NP * NP * sizeof(float), stream);
  k_scatter<<<BG, 256, 0, stream>>>(esrc, edst, eflag, A);
  k_invdeg<<<BG * NP / 256, 256, 0, stream>>>(A, idg);
  k_gemm_agg<<<dim3(8, BG), 256, 0, stream>>>(A, h, idg, agg);
  k_gemm_z<<<BG * NP / 32, 256, 0, stream>>>(h, agg, Wf, Wp, Z);
  k_epi<<<BG * NP, 256, 0, stream>>>(Z, bfe, bpo, feat, assign);
  k_gemm_as<<<dim3(4, BG), 256, 0, stream>>>(A, assign, AS);
  k_pool<<<dim3(4, BG), 256, 0, stream>>>(assign, AS, feat, stage, hpool);

  hipMemsetAsync(adj, 0, ADJ_BYTES, stream);                  // scratch is dead now
  k_emit<<<BG * DO, 128, 0, stream>>>(stage, adj);
}

// Round 12
// 508.000 us; speedup vs baseline: 2.3799x; 1.0597x over previous
//
#include <hip/hip_runtime.h>
#include <hip/hip_bf16.h>
#include <stdint.h>

#define BG 64     // graphs
#define NP 256    // nodes per graph
#define DI 256    // in features
#define DO 128    // out features = clusters
#define EP 8192   // edges per graph

// ALL float tensors are FP32 (R8 probe-decoded; R9-R11 passed). Edges int32 (+int64 vote).

__device__ __forceinline__ int ldi(const void* p, size_t i, int i64) {
  return i64 ? (int)((const long long*)p)[i] : ((const int*)p)[i];
}

// ---- scatter: zero A+deg slabs, per-block int64 vote, then A[b][dst][src]+=1, deg[dst]+=1
__global__ __launch_bounds__(256) void k_scatter(const void* __restrict__ esrc,
                                                 const void* __restrict__ edst,
                                                 float* __restrict__ A,
                                                 float* __restrict__ deg) {
  __shared__ int cnt;
  int b = blockIdx.x, t = threadIdx.x;
  if (t == 0) cnt = 0;
  __syncthreads();
  // dtype vote on words 1,3,...,511 (region valid under both dtypes; identical per block)
  uint32_t w = ((const uint32_t*)esrc)[2 * t + 1];
  if (w != 0) atomicAdd(&cnt, 1);
  // zero this graph's A slab (64 float4/thread) and deg row
  float4* Az = (float4*)(A + (size_t)b * NP * NP);
  for (int i = t; i < NP * NP / 4; i += 256) Az[i] = make_float4(0.f, 0.f, 0.f, 0.f);
  deg[b * NP + t] = 0.f;
  __syncthreads();
  int i64 = (cnt == 0);
  const size_t base = (size_t)b * EP;
  float* Ab = A + (size_t)b * NP * NP;
  float* degb = deg + b * NP;
  for (int e = t; e < EP; e += 256) {
    int si = ldi(esrc, base + e, i64) & (NP - 1);
    int di = ldi(edst, base + e, i64) & (NP - 1);
    atomicAdd(Ab + (size_t)di * NP + si, 1.0f);
    atomicAdd(degb + di, 1.0f);
  }
}

// ---- agg = rowscale(A @ h), scale = 1/max(deg,1); tiled 64x128, thread 4x8 ----
__global__ __launch_bounds__(256) void k_gemm_agg(const float* __restrict__ A,
                                                  const float* __restrict__ h,
                                                  const float* __restrict__ deg,
                                                  float* __restrict__ agg) {
  __shared__ __align__(16) float As[32][68];    // [k][r]
  __shared__ __align__(16) float Hs[32][132];   // [k][f]
  int b = blockIdx.y;
  int r0 = (blockIdx.x & 3) * 64;
  int f0 = (blockIdx.x >> 2) * 128;
  int t = threadIdx.x;
  int tr = t >> 4, tc = t & 15;
  float acc[4][8] = {};
  const float* Ab = A + (size_t)b * NP * NP;
  const float* hb = h + (size_t)b * NP * DI;
  for (int kc = 0; kc < NP; kc += 32) {
    __syncthreads();
    {  // A tile: 64 r x 32 k, transposed to [k][r]
      int r = t >> 2;
      int ks = (t & 3) * 8;
      const float* src = &Ab[(size_t)(r0 + r) * NP + kc + ks];
      float4 v0 = *(const float4*)src;
      float4 v1 = *(const float4*)(src + 4);
      As[ks + 0][r] = v0.x; As[ks + 1][r] = v0.y; As[ks + 2][r] = v0.z; As[ks + 3][r] = v0.w;
      As[ks + 4][r] = v1.x; As[ks + 5][r] = v1.y; As[ks + 6][r] = v1.z; As[ks + 7][r] = v1.w;
    }
    {  // H tile: 32 k x 128 f
      int k = t >> 3;
      int fs = (t & 7) * 16;
      const float* src = &hb[(size_t)(kc + k) * DI + f0 + fs];
#pragma unroll
      for (int j = 0; j < 4; ++j)
        *(float4*)&Hs[k][fs + j * 4] = *(const float4*)(src + j * 4);
    }
    __syncthreads();
#pragma unroll
    for (int k = 0; k < 32; ++k) {
      float a[4], ww[8];
      *(float4*)&a[0] = *(const float4*)&As[k][tr * 4];
      *(float4*)&ww[0] = *(const float4*)&Hs[k][tc * 8];
      *(float4*)&ww[4] = *(const float4*)&Hs[k][tc * 8 + 4];
#pragma unroll
      for (int i = 0; i < 4; ++i)
#pragma unroll
        for (int j = 0; j < 8; ++j)
          acc[i][j] += a[i] * ww[j];
    }
  }
#pragma unroll
  for (int i = 0; i < 4; ++i) {
    int gi = r0 + tr * 4 + i;
    float sc = 1.0f / fmaxf(deg[b * NP + gi], 1.0f);
    float* dst = &agg[((size_t)b * NP + gi) * DI + f0 + tc * 8];
    float o0[4] = { acc[i][0] * sc, acc[i][1] * sc, acc[i][2] * sc, acc[i][3] * sc };
    float o1[4] = { acc[i][4] * sc, acc[i][5] * sc, acc[i][6] * sc, acc[i][7] * sc };
    *(float4*)dst = *(float4*)o0;
    *(float4*)(dst + 4) = *(float4*)o1;
  }
}

// ---- Z = [h|agg]@[Wf|Wp] fused with +bias, L2-norm, relu (+softmax) -> feat, assign ---
// 32 rows x 256 cols per block; per-row reductions via shfl_xor within 16-lane halves.
__global__ __launch_bounds__(256) void k_gemm_zepi(const float* __restrict__ h,
                                                   const float* __restrict__ agg,
                                                   const float* __restrict__ Wf,
                                                   const float* __restrict__ Wp,
                                                   const float* __restrict__ bfe,
                                                   const float* __restrict__ bpo,
                                                   float* __restrict__ feat,
                                                   float* __restrict__ assign) {
  __shared__ __align__(16) float Xs[32][36];    // [k][row]
  __shared__ __align__(16) float Ws[32][264];   // [k][col]
  int r0 = blockIdx.x * 32;
  int t = threadIdx.x;
  int rg = t >> 5;     // row group: rows rg*4..+3
  int cg = t & 31;     // col group: cols cg*8..+7
  float acc[4][8] = {};
  for (int kc = 0; kc < 2 * DI; kc += 32) {
    __syncthreads();
    {  // X chunk
      int r = t >> 3;
      int kk = (t & 7) * 4;
      const float* src = (kc < DI) ? &h[(size_t)(r0 + r) * DI + kc + kk]
                                   : &agg[(size_t)(r0 + r) * DI + (kc - DI) + kk];
      float4 v = *(const float4*)src;
      Xs[kk + 0][r] = v.x; Xs[kk + 1][r] = v.y; Xs[kk + 2][r] = v.z; Xs[kk + 3][r] = v.w;
    }
    {  // W chunk
      int k = t >> 3;
      int cbase = (t & 7) * 32;
      const float* srcW = (cbase < DO) ? &Wf[(size_t)(kc + k) * DO + cbase]
                                       : &Wp[(size_t)(kc + k) * DO + cbase - DO];
#pragma unroll
      for (int j = 0; j < 8; ++j)
        *(float4*)&Ws[k][cbase + j * 4] = *(const float4*)(srcW + j * 4);
    }
    __syncthreads();
#pragma unroll
    for (int kk = 0; kk < 32; ++kk) {
      float a[4], ww[8];
      *(float4*)&a[0] = *(const float4*)&Xs[kk][rg * 4];
      *(float4*)&ww[0] = *(const float4*)&Ws[kk][cg * 8];
      *(float4*)&ww[4] = *(const float4*)&Ws[kk][cg * 8 + 4];
#pragma unroll
      for (int i = 0; i < 4; ++i)
#pragma unroll
        for (int j = 0; j < 8; ++j)
          acc[i][j] += a[i] * ww[j];
    }
  }
  // fused epilogue
  int half = cg >> 4;   // 0 = feat head (cols 0..127), 1 = pool head (cols 128..255)
  float bias[8];
  {
    const float* bp = half ? bpo : bfe;
#pragma unroll
    for (int j = 0; j < 8; ++j) bias[j] = bp ? bp[(cg * 8 + j) & (DO - 1)] : 0.f;
  }
#pragma unroll
  for (int i = 0; i < 4; ++i) {
    int r = r0 + rg * 4 + i;
    float z[8];
    float ss = 0.f;
#pragma unroll
    for (int j = 0; j < 8; ++j) { z[j] = acc[i][j] + bias[j]; ss += z[j] * z[j]; }
    ss += __shfl_xor(ss, 1); ss += __shfl_xor(ss, 2);
    ss += __shfl_xor(ss, 4); ss += __shfl_xor(ss, 8);
    float inv = 1.0f / fmaxf(sqrtf(ss), 1e-12f);
    float v[8];
#pragma unroll
    for (int j = 0; j < 8; ++j) v[j] = fmaxf(z[j] * inv, 0.f);
    if (half == 0) {
      float* dst = &feat[(size_t)r * DO + cg * 8];
      *(float4*)dst = *(float4*)&v[0];
      *(float4*)(dst + 4) = *(float4*)&v[4];
    } else {
      float mx = v[0];
#pragma unroll
      for (int j = 1; j < 8; ++j) mx = fmaxf(mx, v[j]);
      mx = fmaxf(mx, __shfl_xor(mx, 1)); mx = fmaxf(mx, __shfl_xor(mx, 2));
      mx = fmaxf(mx, __shfl_xor(mx, 4)); mx = fmaxf(mx, __shfl_xor(mx, 8));
      float e[8], s = 0.f;
#pragma unroll
      for (int j = 0; j < 8; ++j) { e[j] = __expf(v[j] - mx); s += e[j]; }
      s += __shfl_xor(s, 1); s += __shfl_xor(s, 2);
      s += __shfl_xor(s, 4); s += __shfl_xor(s, 8);
      float is = 1.0f / s;
      float o[8];
#pragma unroll
      for (int j = 0; j < 8; ++j) o[j] = e[j] * is;
      float* dst = &assign[(size_t)r * DO + (cg - 16) * 8];
      *(float4*)dst = *(float4*)&o[0];
      *(float4*)(dst + 4) = *(float4*)&o[4];
    }
  }
}

// ---- AS = A @ assign ; tiled 64x128, thread 4x8 ----
__global__ __launch_bounds__(256) void k_gemm_as(const float* __restrict__ A,
                                                 const float* __restrict__ assign,
                                                 float* __restrict__ AS) {
  __shared__ __align__(16) float As[32][68];
  __shared__ __align__(16) float Bs[32][132];
  int b = blockIdx.y;
  int r0 = blockIdx.x * 64;
  int t = threadIdx.x;
  int tr = t >> 4, tc = t & 15;
  float acc[4][8] = {};
  const float* Ab = A + (size_t)b * NP * NP;
  const float* asb = assign + (size_t)b * NP * DO;
  for (int kc = 0; kc < NP; kc += 32) {
    __syncthreads();
    {
      int r = t >> 2;
      int ks = (t & 3) * 8;
      const float* src = &Ab[(size_t)(r0 + r) * NP + kc + ks];
      float4 v0 = *(const float4*)src;
      float4 v1 = *(const float4*)(src + 4);
      As[ks + 0][r] = v0.x; As[ks + 1][r] = v0.y; As[ks + 2][r] = v0.z; As[ks + 3][r] = v0.w;
      As[ks + 4][r] = v1.x; As[ks + 5][r] = v1.y; As[ks + 6][r] = v1.z; As[ks + 7][r] = v1.w;
    }
    {
      int k = t >> 3;
      int ls = (t & 7) * 16;
      const float* src = &asb[(size_t)(kc + k) * DO + ls];
#pragma unroll
      for (int j = 0; j < 4; ++j)
        *(float4*)&Bs[k][ls + j * 4] = *(const float4*)(src + j * 4);
    }
    __syncthreads();
#pragma unroll
    for (int k = 0; k < 32; ++k) {
      float a[4], ww[8];
      *(float4*)&a[0] = *(const float4*)&As[k][tr * 4];
      *(float4*)&ww[0] = *(const float4*)&Bs[k][tc * 8];
      *(float4*)&ww[4] = *(const float4*)&Bs[k][tc * 8 + 4];
#pragma unroll
      for (int i = 0; i < 4; ++i)
#pragma unroll
        for (int j = 0; j < 8; ++j)
          acc[i][j] += a[i] * ww[j];
    }
  }
#pragma unroll
  for (int i = 0; i < 4; ++i) {
    float* dst = &AS[((size_t)b * NP + r0 + tr * 4 + i) * DO + tc * 8];
    *(float4*)dst = *(float4*)&acc[i][0];
    *(float4*)(dst + 4) = *(float4*)&acc[i][4];
  }
}

// ---- pooling: out = assign^T @ Y ; which 0 -> adj diag block (direct), 1 -> hpool ----
__global__ __launch_bounds__(256) void k_pool(const float* __restrict__ assign,
                                              const float* __restrict__ AS,
                                              const float* __restrict__ feat,
                                              float* __restrict__ adj,
                                              float* __restrict__ hpool) {
  __shared__ __align__(16) float Ps[32][68];
  __shared__ __align__(16) float Ys[32][132];
  int b = blockIdx.y;
  int mt = blockIdx.x & 1;
  int which = blockIdx.x >> 1;
  const float* Y = which ? feat : AS;
  int m0 = mt * 64;
  int t = threadIdx.x;
  int tr = t >> 4, tc = t & 15;
  float acc[4][8] = {};
  for (int nc = 0; nc < NP; nc += 32) {
    __syncthreads();
    {
      int n = t >> 3;
      int mseg = (t & 7) * 8;
      const float* src = &assign[((size_t)b * NP + nc + n) * DO + m0 + mseg];
      *(float4*)&Ps[n][mseg] = *(const float4*)src;
      *(float4*)&Ps[n][mseg + 4] = *(const float4*)(src + 4);
    }
    {
      int n = t >> 3;
      int ds = (t & 7) * 16;
      const float* src = &Y[((size_t)b * NP + nc + n) * DO + ds];
#pragma unroll
      for (int j = 0; j < 4; ++j)
        *(float4*)&Ys[n][ds + j * 4] = *(const float4*)(src + j * 4);
    }
    __syncthreads();
#pragma unroll
    for (int n = 0; n < 32; ++n) {
      float a[4], ww[8];
      *(float4*)&a[0] = *(const float4*)&Ps[n][tr * 4];
      *(float4*)&ww[0] = *(const float4*)&Ys[n][tc * 8];
      *(float4*)&ww[4] = *(const float4*)&Ys[n][tc * 8 + 4];
#pragma unroll
      for (int i = 0; i < 4; ++i)
#pragma unroll
        for (int j = 0; j < 8; ++j)
          acc[i][j] += a[i] * ww[j];
    }
  }
  if (which == 0) {  // adjacency diagonal block, written directly into zeroed adj
#pragma unroll
    for (int i = 0; i < 4; ++i) {
      float* dst = &adj[(size_t)(b * DO + m0 + tr * 4 + i) * (BG * DO) + b * DO + tc * 8];
      *(float4*)dst = *(float4*)&acc[i][0];
      *(float4*)(dst + 4) = *(float4*)&acc[i][4];
    }
  } else {
#pragma unroll
    for (int i = 0; i < 4; ++i) {
      float* dst = &hpool[((size_t)b * DO + m0 + tr * 4 + i) * DO + tc * 8];
      *(float4*)dst = *(float4*)&acc[i][0];
      *(float4*)(dst + 4) = *(float4*)&acc[i][4];
    }
  }
}

extern "C" void kernel_launch(void* const* d_in, const int* in_sizes, int n_in,
                              void* d_out, int out_size, void* d_ws, size_t ws_size,
                              hipStream_t stream) {
  (void)out_size; (void)ws_size;
  int ih = -1, ie[2] = {-1, -1}, iw[2] = {-1, -1}, ib[2] = {-1, -1};
  int ne = 0, nw = 0, nb = 0;
  for (int i = 0; i < n_in; ++i) {
    long long s = in_sizes[i];
    if (s == (long long)BG * NP * DI) { if (ih < 0) ih = i; }
    else if (s == (long long)BG * EP && ne < 2) ie[ne++] = i;
    else if (s == (long long)2 * DI * DO && nw < 2) iw[nw++] = i;
    else if (s == (long long)DO && nb < 2) ib[nb++] = i;
  }
  if (ih < 0 || ne < 2 || nw < 2) {
    ih = 0;
    ie[0] = (n_in > 1) ? 1 : 0;  ie[1] = (n_in > 2) ? 2 : ie[0];
    iw[0] = (n_in > 3) ? 3 : 0;  iw[1] = (n_in > 5) ? 5 : iw[0];
    ib[0] = (n_in > 4) ? 4 : -1; ib[1] = (n_in > 6) ? 6 : -1;
    nb = (ib[1] >= 0) ? 2 : (ib[0] >= 0 ? 1 : 0);
  }
  const float* h    = (const float*)d_in[ih];
  const void* esrc  = d_in[ie[0]];
  const void* edst  = d_in[ie[1]];
  const float* Wf   = (const float*)d_in[iw[0]];
  const float* Wp   = (const float*)d_in[iw[1]];
  const float* bfe  = (nb >= 1) ? (const float*)d_in[ib[0]] : nullptr;
  const float* bpo  = (nb >= 2) ? (const float*)d_in[ib[1]] : nullptr;

  float* adj   = (float*)d_out;
  float* hpool = (float*)d_out + (size_t)(BG * DO) * (BG * DO);
  const size_t ADJ_BYTES = (size_t)(BG * DO) * (BG * DO) * sizeof(float);  // 256 MiB

  // All scratch in d_ws (58,785,792 B total — the R1-proven-safe footprint).
  char* wb = (char*)d_ws;
  float* A      = (float*)wb;                            // 16 MiB
  float* agg    = (float*)(wb + 16777216);               // 16 MiB
  float* feat   = (float*)(wb + 33554432);               //  8 MiB
  float* assign = (float*)(wb + 41943040);               //  8 MiB
  float* AS     = (float*)(wb + 50331648);               //  8 MiB
  float* deg    = (float*)(wb + 58720256);               // 64 KiB

  hipMemsetAsync(adj, 0, ADJ_BYTES, stream);             // first: adj is not scratch anymore
  k_scatter<<<BG, 256, 0, stream>>>(esrc, edst, A, deg);
  k_gemm_agg<<<dim3(8, BG), 256, 0, stream>>>(A, h, deg, agg);
  k_gemm_zepi<<<BG * NP / 32, 256, 0, stream>>>(h, agg, Wf, Wp, bfe, bpo, feat, assign);
  k_gemm_as<<<dim3(4, BG), 256, 0, stream>>>(A, assign, AS);
  k_pool<<<dim3(4, BG), 256, 0, stream>>>(assign, AS, feat, adj, hpool);
}